// Round 7
// baseline (902.236 us; speedup 1.0000x reference)
//
#include <hip/hip_runtime.h>
#include <hip/hip_fp16.h>
#include <math.h>

#define N_NODES 50000
#define EDGES   1600000
#define IN_F    256
#define AD      128
#define H       8
#define DK      16
#define EH      (EDGES * H)          // 12,800,000
#define EPB     512                  // edges per block in edge pass
#define BPH     (EDGES / EPB)        // 3125 blocks per head (exact)

typedef __attribute__((ext_vector_type(8))) _Float16 half8;
typedef __attribute__((ext_vector_type(4))) _Float16 half4;
typedef __attribute__((ext_vector_type(4))) float floatx4;
typedef __attribute__((ext_vector_type(2))) float floatx2;

#ifndef __has_builtin
#define __has_builtin(x) 0
#endif

// ---------------- weight swizzle: fp32 Qw/Kw -> fragment-ready fp16 ------
__global__ void wswz_kernel(const float* __restrict__ Qw,
                            const float* __restrict__ Kw,
                            half8* __restrict__ Wfrag) {
    const int idx = blockIdx.x * blockDim.x + threadIdx.x;  // 8*16*64 = 8192
    if (idx >= 8 * 16 * 64) return;
    const int lane = idx & 63;
    const int nb   = (idx >> 6) & 15;
    const int kb   = idx >> 10;
    const int n    = nb * 16 + (lane & 15);
    const int k0   = kb * 32 + ((lane >> 4) << 3);
    const float* row = (n < AD) ? (Qw + (size_t)n * IN_F)
                                : (Kw + (size_t)(n - AD) * IN_F);
    half8 v;
#pragma unroll
    for (int j = 0; j < 8; j++) v[j] = (_Float16)row[k0 + j];
    Wfrag[idx] = v;
}

// ---------------- MFMA projection -> HEAD-MAJOR q/k ---------------------
// qh/kh layout: [H][N_NODES][16] fp16 (per-head table = 1.6 MB, L2-fit)
#define APAD 264
__global__ __launch_bounds__(256) void proj_mfma_kernel(
    const float* __restrict__ hi, const half8* __restrict__ Wfrag,
    const float* __restrict__ Qb, const float* __restrict__ Kb,
    __half* __restrict__ qh, __half* __restrict__ kh)
{
    __shared__ _Float16 Atile[64][APAD];   // 33.8 KB
    const int r0 = blockIdx.x * 64;
    const int t  = threadIdx.x;

    {
        const int row = t >> 2;
        const int c4  = t & 3;
        const bool valid = (r0 + row) < N_NODES;
        const float4* src = (const float4*)(hi + (size_t)(r0 + row) * IN_F);
#pragma unroll
        for (int i = 0; i < 16; i++) {
            const int col4 = c4 + i * 4;            // float4 index in row
            float4 v = valid ? src[col4] : make_float4(0.f, 0.f, 0.f, 0.f);
            half4 hv;
            hv[0] = (_Float16)v.x; hv[1] = (_Float16)v.y;
            hv[2] = (_Float16)v.z; hv[3] = (_Float16)v.w;
            *(half4*)&Atile[row][col4 * 4] = hv;
        }
    }
    __syncthreads();

    const int wave = t >> 6;
    const int lane = t & 63;
    const int m    = lane & 15;
    const int quad = lane >> 4;

    floatx4 acc[4][4];
#pragma unroll
    for (int a = 0; a < 4; a++)
#pragma unroll
        for (int b = 0; b < 4; b++) acc[a][b] = (floatx4)0.f;

#pragma unroll
    for (int kb = 0; kb < 8; kb++) {
        half8 Af[4], Bf[4];
#pragma unroll
        for (int rb = 0; rb < 4; rb++)
            Af[rb] = *(const half8*)&Atile[rb * 16 + m][kb * 32 + quad * 8];
#pragma unroll
        for (int nbi = 0; nbi < 4; nbi++)
            Bf[nbi] = Wfrag[(size_t)(kb * 16 + wave * 4 + nbi) * 64 + lane];
#pragma unroll
        for (int rb = 0; rb < 4; rb++)
#pragma unroll
            for (int nbi = 0; nbi < 4; nbi++)
                acc[rb][nbi] = __builtin_amdgcn_mfma_f32_16x16x32_f16(
                    Af[rb], Bf[nbi], acc[rb][nbi], 0, 0, 0);
    }

    // epilogue: C/D layout col = lane&15, row = quad*4 + reg
    // head-major write: out[((h*N + row)*16) + d]
#pragma unroll
    for (int nbi = 0; nbi < 4; nbi++) {
        const int n   = wave * 64 + nbi * 16 + m;       // 0..255 combined col
        const float bias = (n < AD) ? Qb[n] : Kb[n - AD];
        __half* out   = (n < AD) ? qh : kh;
        const int ncol = n & (AD - 1);
        const int hh   = ncol >> 4;                     // head
        const int d    = ncol & 15;                     // dim within head
#pragma unroll
        for (int rb = 0; rb < 4; rb++) {
#pragma unroll
            for (int reg = 0; reg < 4; reg++) {
                const int row = r0 + rb * 16 + quad * 4 + reg;
                if (row < N_NODES)
                    out[((size_t)hh * N_NODES + row) * 16 + d] =
                        __float2half(acc[rb][nbi][reg] + bias);
            }
        }
    }
}

// ---------------- per-(head,node) radial constants (head-major) ----------
// cb[h*N+n] = {0.25*sum_d Qrb[h,d]*k, 0.25*sum_d Qrw[h,d]*k}; zeros ssum.
__global__ __launch_bounds__(256) void kprep_kernel(
    const __half* __restrict__ kh, const float* __restrict__ Qrw,
    const float* __restrict__ Qrb, float2* __restrict__ cb,
    float* __restrict__ ssum)
{
    const int n = blockIdx.x * blockDim.x + threadIdx.x;
    const int h = blockIdx.y;
    if (n >= N_NODES) return;
    const size_t idx = (size_t)h * N_NODES + n;
    ssum[idx] = 0.0f;
    const half8* kp = (const half8*)(kh + idx * 16);
    half8 k0 = kp[0], k1 = kp[1];
    const float* rw = Qrw + h * DK;
    const float* rb = Qrb + h * DK;
    float brw = 0.f, crb = 0.f;
#pragma unroll
    for (int i = 0; i < 8; i++) {
        float kf = (float)k0[i];
        brw = fmaf(rw[i], kf, brw);
        crb = fmaf(rb[i], kf, crb);
    }
#pragma unroll
    for (int i = 0; i < 8; i++) {
        float kf = (float)k1[i];
        brw = fmaf(rw[8 + i], kf, brw);
        crb = fmaf(rb[8 + i], kf, crb);
    }
    cb[idx] = make_float2(crb * 0.25f, brw * 0.25f);
}

// ---------------- 16-dim fp16 dot with fp32 accumulate ------------------
__device__ __forceinline__ float dot16(half8 x0, half8 y0, half8 x1, half8 y1) {
#if __has_builtin(__builtin_amdgcn_fdot2)
    typedef _Float16 half2v __attribute__((ext_vector_type(2)));
    float acc = 0.f;
#pragma unroll
    for (int i = 0; i < 4; i++) {
        half2v a = {x0[2 * i], x0[2 * i + 1]};
        half2v b = {y0[2 * i], y0[2 * i + 1]};
        acc = __builtin_amdgcn_fdot2(a, b, acc, false);
    }
#pragma unroll
    for (int i = 0; i < 4; i++) {
        half2v a = {x1[2 * i], x1[2 * i + 1]};
        half2v b = {y1[2 * i], y1[2 * i + 1]};
        acc = __builtin_amdgcn_fdot2(a, b, acc, false);
    }
    return acc;
#else
    float acc = 0.f;
#pragma unroll
    for (int i = 0; i < 8; i++) acc += (float)x0[i] * (float)y0[i];
#pragma unroll
    for (int i = 0; i < 8; i++) acc += (float)x1[i] * (float)y1[i];
    return acc;
#endif
}

// ---------------- edge pass: ONE HEAD PER BLOCK, XCD-pinned -------------
// head = blockIdx&7 -> with round-robin block->XCD dispatch, all gathers
// for head h hit XCD h's private L2 (q_h+k_h+cb_h+ssum_h = 3.8 MiB < 4 MiB).
// Streams (edge, radial, prods_hm) are nt so they don't evict the tables.
__global__ __launch_bounds__(256) void edge_kernel(
    const __half* __restrict__ qh, const __half* __restrict__ kh,
    const float* __restrict__ radial, const int* __restrict__ edge,
    const float2* __restrict__ cb,
    float* __restrict__ prods_hm, float* __restrict__ ssum)
{
    const int h     = blockIdx.x & 7;
    const int chunk = blockIdx.x >> 3;
    const size_t hb = (size_t)h * N_NODES;

    const int eA = chunk * EPB + threadIdx.x;
    const int eB = eA + 256;

    const int e0a = __builtin_nontemporal_load(&edge[eA]);
    const int e1a = __builtin_nontemporal_load(&edge[EDGES + eA]);
    const int e0b = __builtin_nontemporal_load(&edge[eB]);
    const int e1b = __builtin_nontemporal_load(&edge[EDGES + eB]);
    const float ra = __builtin_nontemporal_load(&radial[eA]);
    const float rb = __builtin_nontemporal_load(&radial[eB]);

    const half8* qpa = (const half8*)(qh + (hb + e0a) * 16);
    const half8* kpa = (const half8*)(kh + (hb + e1a) * 16);
    const half8* qpb = (const half8*)(qh + (hb + e0b) * 16);
    const half8* kpb = (const half8*)(kh + (hb + e1b) * 16);
    half8 qa0 = qpa[0], qa1 = qpa[1];
    half8 ka0 = kpa[0], ka1 = kpa[1];
    half8 qb0 = qpb[0], qb1 = qpb[1];
    half8 kb0 = kpb[0], kb1 = kpb[1];
    const floatx2 cba = ((const floatx2*)cb)[hb + e1a];
    const floatx2 cbb = ((const floatx2*)cb)[hb + e1b];

    const float aa = dot16(qa0, ka0, qa1, ka1);
    const float ab = dot16(qb0, kb0, qb1, kb1);

    const float pa = fmaf(0.25f, aa, fmaf(ra, cba.y, cba.x));
    const float pb = fmaf(0.25f, ab, fmaf(rb, cbb.y, cbb.x));

    __builtin_nontemporal_store(pa, &prods_hm[(size_t)h * EDGES + eA]);
    __builtin_nontemporal_store(pb, &prods_hm[(size_t)h * EDGES + eB]);

    atomicAdd(&ssum[hb + e0a], __expf(pa));
    atomicAdd(&ssum[hb + e0b], __expf(pb));
}

// ---------------- normalize + transpose to [E][H] -----------------------
// reads prods_hm coalesced (8 streams), gathers ssum (1.6 MB, cached),
// writes both outputs (prods and att) fully coalesced 32 B per edge.
__global__ __launch_bounds__(256) void norm_kernel(
    const float* __restrict__ prods_hm, const float* __restrict__ ssum,
    const int* __restrict__ edge, float* __restrict__ att,
    float* __restrict__ prods_out)
{
    const int e = blockIdx.x * blockDim.x + threadIdx.x;
    if (e >= EDGES) return;
    const int e0 = edge[e];

    floatx4 p0, p1, a0, a1;
#pragma unroll
    for (int h = 0; h < 4; h++)
        p0[h] = __builtin_nontemporal_load(&prods_hm[(size_t)h * EDGES + e]);
#pragma unroll
    for (int h = 0; h < 4; h++)
        p1[h] = __builtin_nontemporal_load(&prods_hm[(size_t)(h + 4) * EDGES + e]);

#pragma unroll
    for (int h = 0; h < 4; h++) {
        const float s0 = ssum[(size_t)h * N_NODES + e0];
        const float s1 = ssum[(size_t)(h + 4) * N_NODES + e0];
        a0[h] = __expf(p0[h]) * __builtin_amdgcn_rcpf(s0);
        a1[h] = __expf(p1[h]) * __builtin_amdgcn_rcpf(s1);
    }

    floatx4* pp = (floatx4*)(prods_out + (size_t)e * H);
    __builtin_nontemporal_store(p0, pp);
    __builtin_nontemporal_store(p1, pp + 1);
    floatx4* ap = (floatx4*)(att + (size_t)e * H);
    __builtin_nontemporal_store(a0, ap);
    __builtin_nontemporal_store(a1, ap + 1);
}

extern "C" void kernel_launch(void* const* d_in, const int* in_sizes, int n_in,
                              void* d_out, int out_size, void* d_ws, size_t ws_size,
                              hipStream_t stream) {
    const float* hi     = (const float*)d_in[0];
    const float* radial = (const float*)d_in[1];
    const float* Qw     = (const float*)d_in[2];
    const float* Qb     = (const float*)d_in[3];
    const float* Qrw    = (const float*)d_in[4];
    const float* Qrb    = (const float*)d_in[5];
    const float* Kw     = (const float*)d_in[6];
    const float* Kb     = (const float*)d_in[7];
    const int*   edge   = (const int*)d_in[8];

    float* att   = (float*)d_out;                    // [E, H]
    float* prods = att + (size_t)EDGES * H;          // [E, H]

    // workspace (head-major): qh 12.8MB, kh 12.8MB, ssum 1.6MB,
    // Wfrag 128KB, cb 3.2MB, prods_hm 51.2MB  -> ~81.8 MB total
    __half* qh   = (__half*)d_ws;                             // [H][N][16]
    __half* kh   = qh + (size_t)H * N_NODES * 16;             // [H][N][16]
    float*  ssum = (float*)(kh + (size_t)H * N_NODES * 16);   // [H][N]
    half8*  Wfrag = (half8*)(ssum + (size_t)H * N_NODES);     // 8192 * 16 B
    float2* cbuf = (float2*)(Wfrag + 8 * 16 * 64);            // [H][N]
    float*  prods_hm = (float*)(cbuf + (size_t)H * N_NODES);  // [H][E]

    wswz_kernel<<<(8 * 16 * 64 + 255) / 256, 256, 0, stream>>>(Qw, Kw, Wfrag);
    proj_mfma_kernel<<<(N_NODES + 63) / 64, 256, 0, stream>>>(hi, Wfrag, Qb, Kb, qh, kh);
    kprep_kernel<<<dim3((N_NODES + 255) / 256, H), 256, 0, stream>>>(
        kh, Qrw, Qrb, cbuf, ssum);
    edge_kernel<<<BPH * H, 256, 0, stream>>>(qh, kh, radial, edge,
                                             cbuf, prods_hm, ssum);
    norm_kernel<<<(EDGES + 255) / 256, 256, 0, stream>>>(prods_hm, ssum, edge,
                                                         att, prods);
}

// Round 8
// 566.969 us; speedup vs baseline: 1.5913x; 1.5913x over previous
//
#include <hip/hip_runtime.h>
#include <hip/hip_fp16.h>
#include <math.h>

#define N_NODES 50000
#define EDGES   1600000
#define IN_F    256
#define AD      128
#define H       8
#define DK      16
#define EH      (EDGES * H)          // 12,800,000
#define EPB     512                  // edges per block in edge pass
#define BPH     (EDGES / EPB)        // 3125 blocks per head (exact)

typedef __attribute__((ext_vector_type(8))) _Float16 half8;
typedef __attribute__((ext_vector_type(4))) _Float16 half4;
typedef __attribute__((ext_vector_type(4))) float floatx4;
typedef __attribute__((ext_vector_type(2))) float floatx2;

#ifndef __has_builtin
#define __has_builtin(x) 0
#endif

// ---------------- weight swizzle: fp32 Qw/Kw -> fragment-ready fp16 ------
__global__ void wswz_kernel(const float* __restrict__ Qw,
                            const float* __restrict__ Kw,
                            half8* __restrict__ Wfrag) {
    const int idx = blockIdx.x * blockDim.x + threadIdx.x;  // 8*16*64 = 8192
    if (idx >= 8 * 16 * 64) return;
    const int lane = idx & 63;
    const int nb   = (idx >> 6) & 15;
    const int kb   = idx >> 10;
    const int n    = nb * 16 + (lane & 15);
    const int k0   = kb * 32 + ((lane >> 4) << 3);
    const float* row = (n < AD) ? (Qw + (size_t)n * IN_F)
                                : (Kw + (size_t)(n - AD) * IN_F);
    half8 v;
#pragma unroll
    for (int j = 0; j < 8; j++) v[j] = (_Float16)row[k0 + j];
    Wfrag[idx] = v;
}

// ---------------- MFMA projection -> HEAD-MAJOR q/k ---------------------
// qh/kh layout: [H][N_NODES][16] fp16 (per-head table = 1.6 MB, L2-fit)
#define APAD 264
__global__ __launch_bounds__(256) void proj_mfma_kernel(
    const float* __restrict__ hi, const half8* __restrict__ Wfrag,
    const float* __restrict__ Qb, const float* __restrict__ Kb,
    __half* __restrict__ qh, __half* __restrict__ kh)
{
    __shared__ _Float16 Atile[64][APAD];   // 33.8 KB
    const int r0 = blockIdx.x * 64;
    const int t  = threadIdx.x;

    {
        const int row = t >> 2;
        const int c4  = t & 3;
        const bool valid = (r0 + row) < N_NODES;
        const float4* src = (const float4*)(hi + (size_t)(r0 + row) * IN_F);
#pragma unroll
        for (int i = 0; i < 16; i++) {
            const int col4 = c4 + i * 4;            // float4 index in row
            float4 v = valid ? src[col4] : make_float4(0.f, 0.f, 0.f, 0.f);
            half4 hv;
            hv[0] = (_Float16)v.x; hv[1] = (_Float16)v.y;
            hv[2] = (_Float16)v.z; hv[3] = (_Float16)v.w;
            *(half4*)&Atile[row][col4 * 4] = hv;
        }
    }
    __syncthreads();

    const int wave = t >> 6;
    const int lane = t & 63;
    const int m    = lane & 15;
    const int quad = lane >> 4;

    floatx4 acc[4][4];
#pragma unroll
    for (int a = 0; a < 4; a++)
#pragma unroll
        for (int b = 0; b < 4; b++) acc[a][b] = (floatx4)0.f;

#pragma unroll
    for (int kb = 0; kb < 8; kb++) {
        half8 Af[4], Bf[4];
#pragma unroll
        for (int rb = 0; rb < 4; rb++)
            Af[rb] = *(const half8*)&Atile[rb * 16 + m][kb * 32 + quad * 8];
#pragma unroll
        for (int nbi = 0; nbi < 4; nbi++)
            Bf[nbi] = Wfrag[(size_t)(kb * 16 + wave * 4 + nbi) * 64 + lane];
#pragma unroll
        for (int rb = 0; rb < 4; rb++)
#pragma unroll
            for (int nbi = 0; nbi < 4; nbi++)
                acc[rb][nbi] = __builtin_amdgcn_mfma_f32_16x16x32_f16(
                    Af[rb], Bf[nbi], acc[rb][nbi], 0, 0, 0);
    }

    // epilogue: C/D layout col = lane&15, row = quad*4 + reg
    // head-major write: out[((h*N + row)*16) + d]
#pragma unroll
    for (int nbi = 0; nbi < 4; nbi++) {
        const int n   = wave * 64 + nbi * 16 + m;       // 0..255 combined col
        const float bias = (n < AD) ? Qb[n] : Kb[n - AD];
        __half* out   = (n < AD) ? qh : kh;
        const int ncol = n & (AD - 1);
        const int hh   = ncol >> 4;                     // head
        const int d    = ncol & 15;                     // dim within head
#pragma unroll
        for (int rb = 0; rb < 4; rb++) {
#pragma unroll
            for (int reg = 0; reg < 4; reg++) {
                const int row = r0 + rb * 16 + quad * 4 + reg;
                if (row < N_NODES)
                    out[((size_t)hh * N_NODES + row) * 16 + d] =
                        __float2half(acc[rb][nbi][reg] + bias);
            }
        }
    }
}

// ---------------- per-(head,node) radial constants (head-major) ----------
// cb[h*N+n] = {0.25*sum_d Qrb[h,d]*k, 0.25*sum_d Qrw[h,d]*k}.
// Zeros the INTERLEAVED ssum[n*H+h] (for the scatter pass).
__global__ __launch_bounds__(256) void kprep_kernel(
    const __half* __restrict__ kh, const float* __restrict__ Qrw,
    const float* __restrict__ Qrb, float2* __restrict__ cb,
    float* __restrict__ ssum)
{
    const int n = blockIdx.x * blockDim.x + threadIdx.x;
    const int h = blockIdx.y;
    if (n >= N_NODES) return;
    ssum[(size_t)n * H + h] = 0.0f;
    const size_t idx = (size_t)h * N_NODES + n;
    const half8* kp = (const half8*)(kh + idx * 16);
    half8 k0 = kp[0], k1 = kp[1];
    const float* rw = Qrw + h * DK;
    const float* rb = Qrb + h * DK;
    float brw = 0.f, crb = 0.f;
#pragma unroll
    for (int i = 0; i < 8; i++) {
        float kf = (float)k0[i];
        brw = fmaf(rw[i], kf, brw);
        crb = fmaf(rb[i], kf, crb);
    }
#pragma unroll
    for (int i = 0; i < 8; i++) {
        float kf = (float)k1[i];
        brw = fmaf(rw[8 + i], kf, brw);
        crb = fmaf(rb[8 + i], kf, crb);
    }
    cb[idx] = make_float2(crb * 0.25f, brw * 0.25f);
}

// ---------------- 16-dim fp16 dot with fp32 accumulate ------------------
__device__ __forceinline__ float dot16(half8 x0, half8 y0, half8 x1, half8 y1) {
#if __has_builtin(__builtin_amdgcn_fdot2)
    typedef _Float16 half2v __attribute__((ext_vector_type(2)));
    float acc = 0.f;
#pragma unroll
    for (int i = 0; i < 4; i++) {
        half2v a = {x0[2 * i], x0[2 * i + 1]};
        half2v b = {y0[2 * i], y0[2 * i + 1]};
        acc = __builtin_amdgcn_fdot2(a, b, acc, false);
    }
#pragma unroll
    for (int i = 0; i < 4; i++) {
        half2v a = {x1[2 * i], x1[2 * i + 1]};
        half2v b = {y1[2 * i], y1[2 * i + 1]};
        acc = __builtin_amdgcn_fdot2(a, b, acc, false);
    }
    return acc;
#else
    float acc = 0.f;
#pragma unroll
    for (int i = 0; i < 8; i++) acc += (float)x0[i] * (float)y0[i];
#pragma unroll
    for (int i = 0; i < 8; i++) acc += (float)x1[i] * (float)y1[i];
    return acc;
#endif
}

// ---------------- A: edge QK pass, XCD-pinned, NO ATOMICS ---------------
// head = blockIdx&7 pins each head's q/k/cb tables (3.6 MiB) into one
// XCD's L2 (validated: FETCH 440->138 MB in round 7). Atomics removed —
// they were the round-7 disaster (448 MB write storm, line ping-pong).
__global__ __launch_bounds__(256) void edge_qk_kernel(
    const __half* __restrict__ qh, const __half* __restrict__ kh,
    const float* __restrict__ radial, const int* __restrict__ edge,
    const float2* __restrict__ cb, float* __restrict__ prods_hm)
{
    const int h     = blockIdx.x & 7;
    const int chunk = blockIdx.x >> 3;
    const size_t hb = (size_t)h * N_NODES;

    const int eA = chunk * EPB + threadIdx.x;
    const int eB = eA + 256;

    const int e0a = __builtin_nontemporal_load(&edge[eA]);
    const int e1a = __builtin_nontemporal_load(&edge[EDGES + eA]);
    const int e0b = __builtin_nontemporal_load(&edge[eB]);
    const int e1b = __builtin_nontemporal_load(&edge[EDGES + eB]);
    const float ra = __builtin_nontemporal_load(&radial[eA]);
    const float rb = __builtin_nontemporal_load(&radial[eB]);

    const half8* qpa = (const half8*)(qh + (hb + e0a) * 16);
    const half8* kpa = (const half8*)(kh + (hb + e1a) * 16);
    const half8* qpb = (const half8*)(qh + (hb + e0b) * 16);
    const half8* kpb = (const half8*)(kh + (hb + e1b) * 16);
    half8 qa0 = qpa[0], qa1 = qpa[1];
    half8 ka0 = kpa[0], ka1 = kpa[1];
    half8 qb0 = qpb[0], qb1 = qpb[1];
    half8 kb0 = kpb[0], kb1 = kpb[1];
    const floatx2 cba = ((const floatx2*)cb)[hb + e1a];
    const floatx2 cbb = ((const floatx2*)cb)[hb + e1b];

    const float aa = dot16(qa0, ka0, qa1, ka1);
    const float ab = dot16(qb0, kb0, qb1, kb1);

    const float pa = fmaf(0.25f, aa, fmaf(ra, cba.y, cba.x));
    const float pb = fmaf(0.25f, ab, fmaf(rb, cbb.y, cbb.x));

    __builtin_nontemporal_store(pa, &prods_hm[(size_t)h * EDGES + eA]);
    __builtin_nontemporal_store(pb, &prods_hm[(size_t)h * EDGES + eB]);
}

// ---------------- B: scatter-sum with line-merged atomics ---------------
// round-6 mapping: 8 lanes = 8 heads of one edge -> their atomics target
// one 32B segment of ssum[e0*H..] and merge into a single line-op.
__global__ __launch_bounds__(256) void scatter_kernel(
    const float* __restrict__ prods_hm, const int* __restrict__ edge,
    float* __restrict__ ssum)
{
    const int t = blockIdx.x * blockDim.x + threadIdx.x;  // [0, EH)
    const int e = t >> 3;
    const int h = t & 7;
    const float p = __builtin_nontemporal_load(&prods_hm[(size_t)h * EDGES + e]);
    const int e0 = edge[e];
    atomicAdd(&ssum[(size_t)e0 * H + h], __expf(p));
}

// ---------------- C: normalize + transpose to [E][H] --------------------
__global__ __launch_bounds__(256) void norm_kernel(
    const float* __restrict__ prods_hm, const float* __restrict__ ssum,
    const int* __restrict__ edge, float* __restrict__ att,
    float* __restrict__ prods_out)
{
    const int e = blockIdx.x * blockDim.x + threadIdx.x;
    if (e >= EDGES) return;
    const int e0 = edge[e];

    floatx4 p0, p1, a0, a1;
#pragma unroll
    for (int h = 0; h < 4; h++)
        p0[h] = __builtin_nontemporal_load(&prods_hm[(size_t)h * EDGES + e]);
#pragma unroll
    for (int h = 0; h < 4; h++)
        p1[h] = __builtin_nontemporal_load(&prods_hm[(size_t)(h + 4) * EDGES + e]);

    const floatx4* sp = (const floatx4*)(ssum + (size_t)e0 * H);
    floatx4 s0 = sp[0], s1 = sp[1];
#pragma unroll
    for (int h = 0; h < 4; h++) {
        a0[h] = __expf(p0[h]) * __builtin_amdgcn_rcpf(s0[h]);
        a1[h] = __expf(p1[h]) * __builtin_amdgcn_rcpf(s1[h]);
    }

    floatx4* pp = (floatx4*)(prods_out + (size_t)e * H);
    __builtin_nontemporal_store(p0, pp);
    __builtin_nontemporal_store(p1, pp + 1);
    floatx4* ap = (floatx4*)(att + (size_t)e * H);
    __builtin_nontemporal_store(a0, ap);
    __builtin_nontemporal_store(a1, ap + 1);
}

extern "C" void kernel_launch(void* const* d_in, const int* in_sizes, int n_in,
                              void* d_out, int out_size, void* d_ws, size_t ws_size,
                              hipStream_t stream) {
    const float* hi     = (const float*)d_in[0];
    const float* radial = (const float*)d_in[1];
    const float* Qw     = (const float*)d_in[2];
    const float* Qb     = (const float*)d_in[3];
    const float* Qrw    = (const float*)d_in[4];
    const float* Qrb    = (const float*)d_in[5];
    const float* Kw     = (const float*)d_in[6];
    const float* Kb     = (const float*)d_in[7];
    const int*   edge   = (const int*)d_in[8];

    float* att   = (float*)d_out;                    // [E, H]
    float* prods = att + (size_t)EDGES * H;          // [E, H]

    // workspace: qh 12.8MB, kh 12.8MB, ssum 1.6MB (interleaved [N][H]),
    // Wfrag 128KB, cb 3.2MB (head-major), prods_hm 51.2MB -> ~82 MB
    __half* qh   = (__half*)d_ws;                             // [H][N][16]
    __half* kh   = qh + (size_t)H * N_NODES * 16;             // [H][N][16]
    float*  ssum = (float*)(kh + (size_t)H * N_NODES * 16);   // [N][H]
    half8*  Wfrag = (half8*)(ssum + (size_t)N_NODES * H);     // 8192 * 16 B
    float2* cbuf = (float2*)(Wfrag + 8 * 16 * 64);            // [H][N]
    float*  prods_hm = (float*)(cbuf + (size_t)H * N_NODES);  // [H][E]

    wswz_kernel<<<(8 * 16 * 64 + 255) / 256, 256, 0, stream>>>(Qw, Kw, Wfrag);
    proj_mfma_kernel<<<(N_NODES + 63) / 64, 256, 0, stream>>>(hi, Wfrag, Qb, Kb, qh, kh);
    kprep_kernel<<<dim3((N_NODES + 255) / 256, H), 256, 0, stream>>>(
        kh, Qrw, Qrb, cbuf, ssum);
    edge_qk_kernel<<<BPH * H, 256, 0, stream>>>(qh, kh, radial, edge,
                                                cbuf, prods_hm);
    scatter_kernel<<<EH / 256, 256, 0, stream>>>(prods_hm, edge, ssum);
    norm_kernel<<<(EDGES + 255) / 256, 256, 0, stream>>>(prods_hm, ssum, edge,
                                                         att, prods);
}

// Round 9
// 356.151 us; speedup vs baseline: 2.5333x; 1.5919x over previous
//
#include <hip/hip_runtime.h>
#include <hip/hip_fp16.h>
#include <math.h>

#define N_NODES 50000
#define EDGES   1600000
#define IN_F    256
#define AD      128
#define H       8
#define DK      16

typedef __attribute__((ext_vector_type(8))) _Float16 half8;
typedef __attribute__((ext_vector_type(4))) _Float16 half4;
typedef __attribute__((ext_vector_type(4))) float floatx4;

#ifndef __has_builtin
#define __has_builtin(x) 0
#endif

// ---------------- weight swizzle: fp32 Qw/Kw -> fragment-ready fp16 ------
__global__ void wswz_kernel(const float* __restrict__ Qw,
                            const float* __restrict__ Kw,
                            half8* __restrict__ Wfrag) {
    const int idx = blockIdx.x * blockDim.x + threadIdx.x;  // 8*16*64 = 8192
    if (idx >= 8 * 16 * 64) return;
    const int lane = idx & 63;
    const int nb   = (idx >> 6) & 15;
    const int kb   = idx >> 10;
    const int n    = nb * 16 + (lane & 15);
    const int k0   = kb * 32 + ((lane >> 4) << 3);
    const float* row = (n < AD) ? (Qw + (size_t)n * IN_F)
                                : (Kw + (size_t)(n - AD) * IN_F);
    half8 v;
#pragma unroll
    for (int j = 0; j < 8; j++) v[j] = (_Float16)row[k0 + j];
    Wfrag[idx] = v;
}

// ---------------- MFMA projection: [64 rows x 256 cols] per block --------
#define APAD 264
__global__ __launch_bounds__(256) void proj_mfma_kernel(
    const float* __restrict__ hi, const half8* __restrict__ Wfrag,
    const float* __restrict__ Qb, const float* __restrict__ Kb,
    __half* __restrict__ qh, __half* __restrict__ kh)
{
    __shared__ _Float16 Atile[64][APAD];   // 33.8 KB
    const int r0 = blockIdx.x * 64;
    const int t  = threadIdx.x;

    {
        const int row = t >> 2;
        const int c4  = t & 3;
        const bool valid = (r0 + row) < N_NODES;
        const float4* src = (const float4*)(hi + (size_t)(r0 + row) * IN_F);
#pragma unroll
        for (int i = 0; i < 16; i++) {
            const int col4 = c4 + i * 4;            // float4 index in row
            float4 v = valid ? src[col4] : make_float4(0.f, 0.f, 0.f, 0.f);
            half4 hv;
            hv[0] = (_Float16)v.x; hv[1] = (_Float16)v.y;
            hv[2] = (_Float16)v.z; hv[3] = (_Float16)v.w;
            *(half4*)&Atile[row][col4 * 4] = hv;
        }
    }
    __syncthreads();

    const int wave = t >> 6;
    const int lane = t & 63;
    const int m    = lane & 15;
    const int quad = lane >> 4;

    floatx4 acc[4][4];
#pragma unroll
    for (int a = 0; a < 4; a++)
#pragma unroll
        for (int b = 0; b < 4; b++) acc[a][b] = (floatx4)0.f;

#pragma unroll
    for (int kb = 0; kb < 8; kb++) {
        half8 Af[4], Bf[4];
#pragma unroll
        for (int rb = 0; rb < 4; rb++)
            Af[rb] = *(const half8*)&Atile[rb * 16 + m][kb * 32 + quad * 8];
#pragma unroll
        for (int nbi = 0; nbi < 4; nbi++)
            Bf[nbi] = Wfrag[(size_t)(kb * 16 + wave * 4 + nbi) * 64 + lane];
#pragma unroll
        for (int rb = 0; rb < 4; rb++)
#pragma unroll
            for (int nbi = 0; nbi < 4; nbi++)
                acc[rb][nbi] = __builtin_amdgcn_mfma_f32_16x16x32_f16(
                    Af[rb], Bf[nbi], acc[rb][nbi], 0, 0, 0);
    }

    // epilogue: C/D layout col = lane&15, row = quad*4 + reg
#pragma unroll
    for (int nbi = 0; nbi < 4; nbi++) {
        const int n   = wave * 64 + nbi * 16 + m;
        const float bias = (n < AD) ? Qb[n] : Kb[n - AD];
        __half* out   = (n < AD) ? qh : kh;
        const int ncol = n & (AD - 1);
#pragma unroll
        for (int rb = 0; rb < 4; rb++) {
#pragma unroll
            for (int reg = 0; reg < 4; reg++) {
                const int row = r0 + rb * 16 + quad * 4 + reg;
                if (row < N_NODES)
                    out[(size_t)row * AD + ncol] = __float2half(acc[rb][nbi][reg] + bias);
            }
        }
    }
}

// ---------------- per-(node,head) radial-projection constants ------------
// cb[n,h] = {0.25*sum_d Qrb[h,d]*k, 0.25*sum_d Qrw[h,d]*k}; zeros ssum too.
__global__ __launch_bounds__(256) void kprep_kernel(
    const __half* __restrict__ kh, const float* __restrict__ Qrw,
    const float* __restrict__ Qrb, float2* __restrict__ cb,
    float* __restrict__ ssum)
{
    const int t = blockIdx.x * blockDim.x + threadIdx.x;
    if (t >= N_NODES * H) return;
    ssum[t] = 0.0f;
    const int h = t & 7;
    const half8* kp = (const half8*)(kh + (size_t)(t >> 3) * AD + h * DK);
    half8 k0 = kp[0], k1 = kp[1];
    const float* rw = Qrw + h * DK;
    const float* rb = Qrb + h * DK;
    float brw = 0.f, crb = 0.f;
#pragma unroll
    for (int i = 0; i < 8; i++) {
        float kf = (float)k0[i];
        brw = fmaf(rw[i], kf, brw);
        crb = fmaf(rb[i], kf, crb);
    }
#pragma unroll
    for (int i = 0; i < 8; i++) {
        float kf = (float)k1[i];
        brw = fmaf(rw[8 + i], kf, brw);
        crb = fmaf(rb[8 + i], kf, crb);
    }
    cb[t] = make_float2(crb * 0.25f, brw * 0.25f);
}

// ---------------- 16-dim fp16 dot with fp32 accumulate ------------------
__device__ __forceinline__ float dot16(half8 x0, half8 y0, half8 x1, half8 y1) {
#if __has_builtin(__builtin_amdgcn_fdot2)
    typedef _Float16 half2v __attribute__((ext_vector_type(2)));
    float acc = 0.f;
#pragma unroll
    for (int i = 0; i < 4; i++) {
        half2v a = {x0[2 * i], x0[2 * i + 1]};
        half2v b = {y0[2 * i], y0[2 * i + 1]};
        acc = __builtin_amdgcn_fdot2(a, b, acc, false);
    }
#pragma unroll
    for (int i = 0; i < 4; i++) {
        half2v a = {x1[2 * i], x1[2 * i + 1]};
        half2v b = {y1[2 * i], y1[2 * i + 1]};
        acc = __builtin_amdgcn_fdot2(a, b, acc, false);
    }
    return acc;
#else
    float acc = 0.f;
#pragma unroll
    for (int i = 0; i < 8; i++) acc += (float)x0[i] * (float)y0[i];
#pragma unroll
    for (int i = 0; i < 8; i++) acc += (float)x1[i] * (float)y1[i];
    return acc;
#endif
}

// ---------------- edge pass: one THREAD per (edge-pair, head) -----------
// Best-measured structure (138 us): interleaved [N][AD] q/k so the 8
// heads of an edge-octet read one contiguous 256 B row (full-line
// coalescing) and their ssum atomics merge into a single line-op.
__global__ __launch_bounds__(256, 6) void edge_kernel(
    const __half* __restrict__ qh, const __half* __restrict__ kh,
    const float* __restrict__ radial, const int* __restrict__ edge,
    const float2* __restrict__ cb,
    float* __restrict__ prods, float* __restrict__ ssum)
{
    const int t = blockIdx.x * blockDim.x + threadIdx.x;  // [0, E*H/2)
    const int e = t >> 3;
    const int h = t & 7;
    if (e >= EDGES / 2) return;
    const int eB = e + EDGES / 2;

    // issue all index loads first
    const int e0a = edge[e];
    const int e1a = edge[EDGES + e];
    const int e0b = edge[eB];
    const int e1b = edge[EDGES + eB];

    // issue all gathers (independent chains)
    const half8* qpa = (const half8*)(qh + (size_t)e0a * AD + h * DK);
    const half8* kpa = (const half8*)(kh + (size_t)e1a * AD + h * DK);
    const half8* qpb = (const half8*)(qh + (size_t)e0b * AD + h * DK);
    const half8* kpb = (const half8*)(kh + (size_t)e1b * AD + h * DK);
    half8 qa0 = qpa[0], qa1 = qpa[1];
    half8 ka0 = kpa[0], ka1 = kpa[1];
    half8 qb0 = qpb[0], qb1 = qpb[1];
    half8 kb0 = kpb[0], kb1 = kpb[1];
    const float2 cba = cb[(size_t)e1a * H + h];
    const float2 cbb = cb[(size_t)e1b * H + h];
    const float ra = __builtin_nontemporal_load(&radial[e]);
    const float rb = __builtin_nontemporal_load(&radial[eB]);

    const float aa = dot16(qa0, ka0, qa1, ka1);
    const float ab = dot16(qb0, kb0, qb1, kb1);

    const float pa = fmaf(0.25f, aa, fmaf(ra, cba.y, cba.x));
    const float pb = fmaf(0.25f, ab, fmaf(rb, cbb.y, cbb.x));

    __builtin_nontemporal_store(pa, &prods[(size_t)e * H + h]);
    __builtin_nontemporal_store(pb, &prods[(size_t)eB * H + h]);

    atomicAdd(&ssum[e0a * H + h], __expf(pa));
    atomicAdd(&ssum[e0b * H + h], __expf(pb));
}

// ---------------- normalize: att = exp(p) / ssum[e0,h], one edge/thread -
__global__ __launch_bounds__(256) void norm_kernel(
    const float* __restrict__ prods, const float* __restrict__ ssum,
    const int* __restrict__ edge, float* __restrict__ att)
{
    const int e = blockIdx.x * blockDim.x + threadIdx.x;
    if (e >= EDGES) return;
    const int e0 = edge[e];
    const floatx4* pp = (const floatx4*)(prods + (size_t)e * H);
    floatx4 p0 = __builtin_nontemporal_load(pp);
    floatx4 p1 = __builtin_nontemporal_load(pp + 1);
    const floatx4* sp = (const floatx4*)(ssum + (size_t)e0 * H);
    floatx4 s0 = sp[0], s1 = sp[1];
    floatx4 a0, a1;
#pragma unroll
    for (int i = 0; i < 4; i++) {
        a0[i] = __expf(p0[i]) / s0[i];
        a1[i] = __expf(p1[i]) / s1[i];
    }
    floatx4* ap = (floatx4*)(att + (size_t)e * H);
    __builtin_nontemporal_store(a0, ap);
    __builtin_nontemporal_store(a1, ap + 1);
}

extern "C" void kernel_launch(void* const* d_in, const int* in_sizes, int n_in,
                              void* d_out, int out_size, void* d_ws, size_t ws_size,
                              hipStream_t stream) {
    const float* hi     = (const float*)d_in[0];
    const float* radial = (const float*)d_in[1];
    const float* Qw     = (const float*)d_in[2];
    const float* Qb     = (const float*)d_in[3];
    const float* Qrw    = (const float*)d_in[4];
    const float* Qrb    = (const float*)d_in[5];
    const float* Kw     = (const float*)d_in[6];
    const float* Kb     = (const float*)d_in[7];
    const int*   edge   = (const int*)d_in[8];

    float* att   = (float*)d_out;                    // [E, H]
    float* prods = att + (size_t)EDGES * H;          // [E, H]

    __half* qh   = (__half*)d_ws;                             // N*AD fp16
    __half* kh   = qh + (size_t)N_NODES * AD;                 // N*AD fp16
    float*  ssum = (float*)(kh + (size_t)N_NODES * AD);       // N*H fp32
    half8*  Wfrag = (half8*)(ssum + (size_t)N_NODES * H);     // 8192 * 16 B
    float2* cbuf = (float2*)(Wfrag + 8 * 16 * 64);            // N*H float2

    wswz_kernel<<<(8 * 16 * 64 + 255) / 256, 256, 0, stream>>>(Qw, Kw, Wfrag);
    proj_mfma_kernel<<<(N_NODES + 63) / 64, 256, 0, stream>>>(hi, Wfrag, Qb, Kb, qh, kh);
    kprep_kernel<<<(N_NODES * H + 255) / 256, 256, 0, stream>>>(kh, Qrw, Qrb, cbuf, ssum);
    edge_kernel<<<(EDGES * H / 2 + 255) / 256, 256, 0, stream>>>(qh, kh, radial, edge,
                                                                 cbuf, prods, ssum);
    norm_kernel<<<(EDGES + 255) / 256, 256, 0, stream>>>(prods, ssum, edge, att);
}